// Round 2
// baseline (895.581 us; speedup 1.0000x reference)
//
#include <hip/hip_runtime.h>
#include <hip/hip_bf16.h>
#include <math.h>

// MoE top-2, E=8, D=1024, F=2048, N=8192 tokens.
// R5: port both grouped GEMMs to the 256x256 / 8-wave / BK=64 phase-split
// schedule (T3+T4 counted vmcnt, T5 setprio, T2 swizzle), replacing the
// 128^2 2-phase structure that plateaued at ~317 TF (R0-R4 invariant).
// Per K-tile: 4 phases (M-half x K-slice quadrants, 16 MFMA each); each
// phase stages ONE granule (A or B, one 32-K slice) of the NEXT tile
// (2 global_load_lds per wave); vmcnt(4) at phases 1 and 3 only.
// Ledger (per wave, 2 loads/granule):
//   prologue: stage A0,B0,A1,B1 of tile0 (8), vmcnt(4) -> A0,B0 landed.
//   tile t: p0 stage A0(t+1) [6], p1 stage B0(t+1) [8], vmcnt(4) ->
//           A1(t),B1(t) landed (read at p2/p3); p2 stage A1(t+1) [6],
//           p3 stage B1(t+1) [8], vmcnt(4) -> A0(t+1),B0(t+1) landed.
//   Overwrite of a granule is issued >=2 barriers after its last read.

#define E_ 8
#define D_ 1024
#define F_ 2048
#define N_ 8192
#define MAX_MTILES 72                  // ceil((N*K + E*255)/256)
#define MAX_SLOTS (MAX_MTILES * 256)   // 18432

typedef __attribute__((ext_vector_type(8))) short short8;
typedef __attribute__((ext_vector_type(4))) float f32x4;
typedef unsigned short u16;

__device__ __forceinline__ u16 f2bf(float f) {
  unsigned int u = __float_as_uint(f);
  unsigned int r = (u + 0x7fffu + ((u >> 16) & 1u)) >> 16;  // RNE
  return (u16)r;
}

__device__ __forceinline__ void gload_lds16(const void* g, void* lds) {
  __builtin_amdgcn_global_load_lds(
      (const __attribute__((address_space(1))) unsigned int*)g,
      (__attribute__((address_space(3))) unsigned int*)lds,
      16, 0, 0);
}

__device__ __forceinline__ void raw_barrier() {
  asm volatile("s_barrier" ::: "memory");
}
__device__ __forceinline__ void wait_vmcnt4() {
  asm volatile("s_waitcnt vmcnt(4)" ::: "memory");
}

// ---------------- router: one wave per token ----------------
__global__ __launch_bounds__(256) void router_kernel(
    const float* __restrict__ x, const float* __restrict__ Wr,
    int* __restrict__ texp, float* __restrict__ tgate, int* __restrict__ counts) {
  const int token = blockIdx.x * 4 + (threadIdx.x >> 6);
  const int lane = threadIdx.x & 63;
  const float4* xr = (const float4*)(x + (size_t)token * D_);
  float acc[E_];
#pragma unroll
  for (int e = 0; e < E_; ++e) acc[e] = 0.f;
#pragma unroll
  for (int it = 0; it < 4; ++it) {
    const int c4 = it * 64 + lane;
    const float4 xv = xr[c4];
#pragma unroll
    for (int e = 0; e < E_; ++e) {
      const float4 wv = ((const float4*)(Wr + e * D_))[c4];
      acc[e] += xv.x * wv.x + xv.y * wv.y + xv.z * wv.z + xv.w * wv.w;
    }
  }
#pragma unroll
  for (int e = 0; e < E_; ++e)
#pragma unroll
    for (int s = 32; s > 0; s >>= 1) acc[e] += __shfl_xor(acc[e], s, 64);
  if (lane == 0) {
    int e0 = 0;
#pragma unroll
    for (int e = 1; e < E_; ++e) if (acc[e] > acc[e0]) e0 = e;
    int e1 = (e0 == 0) ? 1 : 0;
#pragma unroll
    for (int e = 0; e < E_; ++e) if (e != e0 && acc[e] > acc[e1]) e1 = e;
    const float g0 = 1.f / (1.f + __expf(acc[e1] - acc[e0]));
    texp[2 * token] = e0; texp[2 * token + 1] = e1;
    tgate[2 * token] = g0; tgate[2 * token + 1] = 1.f - g0;
    atomicAdd(&counts[e0], 1);
    atomicAdd(&counts[e1], 1);
  }
}

__global__ void offsets_kernel(const int* __restrict__ counts,
                               int* __restrict__ off, int* __restrict__ cursors) {
  if (threadIdx.x == 0) {
    int o = 0;
    for (int e = 0; e < E_; ++e) {
      off[e] = o; cursors[e] = o;
      o += (counts[e] + 255) & ~255;
    }
    off[E_] = o;
  }
}

__global__ void initslots_kernel(int* __restrict__ tok, float* __restrict__ gate) {
  const int s = blockIdx.x * 256 + threadIdx.x;
  tok[s] = 0;
  gate[s] = 0.f;
}

__global__ void place_kernel(const int* __restrict__ texp, const float* __restrict__ tgate,
                             int* __restrict__ cursors, int* __restrict__ tok,
                             float* __restrict__ gate) {
  const int n = blockIdx.x * 256 + threadIdx.x;
  if (n >= N_) return;
#pragma unroll
  for (int k = 0; k < 2; ++k) {
    const int e = texp[2 * n + k];
    const int p = atomicAdd(&cursors[e], 1);
    tok[p] = n;
    gate[p] = tgate[2 * n + k];
  }
}

// ---------------- casts ----------------
__global__ __launch_bounds__(256) void cast_x_kernel(const float* __restrict__ x,
                                                     u16* __restrict__ xb) {
  const int i = blockIdx.x * 256 + threadIdx.x;
  const float4 v = ((const float4*)x)[i];
  ushort4 o;
  o.x = f2bf(v.x); o.y = f2bf(v.y); o.z = f2bf(v.z); o.w = f2bf(v.w);
  ((ushort4*)xb)[i] = o;
}

// in[e][r][c] (fp32) -> out[e][c][r] (bf16); 64x64 tiles, coalesced both sides.
__global__ __launch_bounds__(256) void transpose_cast_kernel(
    const float* __restrict__ in, u16* __restrict__ out, int R, int C) {
  __shared__ float tile[64][65];
  const int e = blockIdx.z;
  const int c0 = blockIdx.x * 64, r0 = blockIdx.y * 64;
  const float* src = in + (size_t)e * R * C;
  u16* dst = out + (size_t)e * R * C;
  const int t = threadIdx.x;
  const int rr = t >> 4;        // 0..15
  const int cc = t & 15;        // 0..15
#pragma unroll
  for (int p = 0; p < 4; ++p) {
    const int r = rr + p * 16;
    const float4 v = *(const float4*)&src[(size_t)(r0 + r) * C + c0 + cc * 4];
    tile[r][cc * 4 + 0] = v.x; tile[r][cc * 4 + 1] = v.y;
    tile[r][cc * 4 + 2] = v.z; tile[r][cc * 4 + 3] = v.w;
  }
  __syncthreads();
#pragma unroll
  for (int p = 0; p < 4; ++p) {
    const int c = rr + p * 16;       // dst row = source col
    const int j = cc * 4;
    ushort4 o;
    o.x = f2bf(tile[j + 0][c]);
    o.y = f2bf(tile[j + 1][c]);
    o.z = f2bf(tile[j + 2][c]);
    o.w = f2bf(tile[j + 3][c]);
    *(ushort4*)&dst[(size_t)(c0 + c) * R + r0 + j] = o;
  }
}

// ---------------- 256x256 / 8-wave / BK=64 phase-split grouped GEMMs -------
// LDS (u16 units): As/Bs[2 buf][2 ks][256 rows][32 k], 64KB each = 128KB.
// Granule staging: wave w, load j covers rows w*32+j*16..+15 linearly;
// lane l writes phys chunk (l&3) of row (l>>2); source k-chunk =
// (l&3)^((l>>3)&3)  (inverse-swizzle on the global side, T2/m173 pattern).
// Read: row = *+lc, phys chunk = lg ^ ((lc>>1)&3).

#define RD_A(ks, mi) \
  (*(const short8*)&As[bufo + (ks) * 8192 + (wm * 128 + (mi) * 16 + lc) * 32 + kch8])
#define RD_B(ks, ni) \
  (*(const short8*)&Bs[bufo + (ks) * 8192 + (wn * 64 + (ni) * 16 + lc) * 32 + kch8])
#define STAGE_A(dbuf, ks, koff) do { \
    gload_lds16(gA0 + (koff) + (ks) * 32, &As[(dbuf) * 16384 + (ks) * 8192 + w * 1024]); \
    gload_lds16(gA1 + (koff) + (ks) * 32, &As[(dbuf) * 16384 + (ks) * 8192 + w * 1024 + 512]); \
  } while (0)
#define STAGE_B(dbuf, ks, koff) do { \
    gload_lds16(gB0 + (koff) + (ks) * 32, &Bs[(dbuf) * 16384 + (ks) * 8192 + w * 1024]); \
    gload_lds16(gB1 + (koff) + (ks) * 32, &Bs[(dbuf) * 16384 + (ks) * 8192 + w * 1024 + 512]); \
  } while (0)

#define MFMA_CLUSTER(mbase) do { \
    __builtin_amdgcn_s_setprio(1); \
    _Pragma("unroll") \
    for (int mi = 0; mi < 4; ++mi) \
      _Pragma("unroll") \
      for (int ni = 0; ni < 4; ++ni) \
        acc[(mbase) + mi][ni] = __builtin_amdgcn_mfma_f32_16x16x32_bf16( \
            aR[mi], bR[ni], acc[(mbase) + mi][ni], 0, 0, 0); \
    __builtin_amdgcn_s_setprio(0); \
  } while (0)

// GEMM1: h[slot,f] = gelu( sum_d xb[tok[slot],d] * W1t[e][f,d] + b1[e][f] )
__global__ __launch_bounds__(512, 2) void gemm1_kernel(
    const u16* __restrict__ xb, const u16* __restrict__ w1t,
    const float* __restrict__ b1, const int* __restrict__ tok,
    const int* __restrict__ off, u16* __restrict__ h) {
  __shared__ __align__(16) u16 As[32768];
  __shared__ __align__(16) u16 Bs[32768];
  const int b = blockIdx.x;
  const int xcd = b & 7;
  const int local = b >> 3;            // 0..71
  const int tn = local & 7;            // 8 N-tiles (F/256)
  const int tm = xcd * 9 + (local >> 3);
  const int base = tm * 256;
  if (base >= off[E_]) return;
  int e = 0;
#pragma unroll
  for (int i = 1; i < E_; ++i) if (base >= off[i]) e = i;

  const int t = threadIdx.x;
  const int w = t >> 6, l = t & 63;
  // staging source
  const int srow = w * 32 + (l >> 2);
  const int scol = ((l & 3) ^ ((l >> 3) & 3)) * 8;   // swizzled 16B chunk
  const u16* gA0 = xb + (size_t)tok[base + srow] * D_ + scol;
  const u16* gA1 = xb + (size_t)tok[base + srow + 16] * D_ + scol;
  const int nr = tn * 256 + srow;
  const u16* gB0 = w1t + ((size_t)e * F_ + nr) * D_ + scol;
  const u16* gB1 = w1t + ((size_t)e * F_ + nr + 16) * D_ + scol;
  // compute-side ids
  const int wm = w >> 2, wn = w & 3;      // 2 M-waves x 4 N-waves
  const int lc = l & 15, lg = l >> 4;
  const int kch8 = (lg ^ ((lc >> 1) & 3)) * 8;

  f32x4 acc[8][4];
#pragma unroll
  for (int i = 0; i < 8; ++i)
#pragma unroll
    for (int j = 0; j < 4; ++j) acc[i][j] = (f32x4)(0.f);

  // prologue: tile 0 fully staged (A0,B0,A1,B1), wait first 2 granules
  STAGE_A(0, 0, 0);
  STAGE_B(0, 0, 0);
  STAGE_A(0, 1, 0);
  STAGE_B(0, 1, 0);
  wait_vmcnt4();
  raw_barrier();

  const int KT = D_ / 64;  // 16
  for (int kt = 0; kt < KT; ++kt) {
    const int buf = kt & 1, nbuf = buf ^ 1;
    const int bufo = buf * 16384;
    // tail: redundant reload of last tile into the dead buffer keeps vmcnt
    // arithmetic uniform; never read.
    const int koff = ((kt + 1 < KT) ? kt + 1 : kt) * 64;
    short8 aR[4], bR[4];
    // ---- p0: M-half 0, ks 0 ----
#pragma unroll
    for (int mi = 0; mi < 4; ++mi) aR[mi] = RD_A(0, mi);
#pragma unroll
    for (int ni = 0; ni < 4; ++ni) bR[ni] = RD_B(0, ni);
    STAGE_A(nbuf, 0, koff);
    raw_barrier();
    MFMA_CLUSTER(0);
    raw_barrier();
    // ---- p1: M-half 1, ks 0 ----
#pragma unroll
    for (int mi = 0; mi < 4; ++mi) aR[mi] = RD_A(0, mi + 4);
    STAGE_B(nbuf, 0, koff);
    raw_barrier();
    MFMA_CLUSTER(4);
    wait_vmcnt4();   // ks1 of current tile landed (read next phase)
    raw_barrier();
    // ---- p2: M-half 0, ks 1 ----
#pragma unroll
    for (int mi = 0; mi < 4; ++mi) aR[mi] = RD_A(1, mi);
#pragma unroll
    for (int ni = 0; ni < 4; ++ni) bR[ni] = RD_B(1, ni);
    STAGE_A(nbuf, 1, koff);
    raw_barrier();
    MFMA_CLUSTER(0);
    raw_barrier();
    // ---- p3: M-half 1, ks 1 ----
#pragma unroll
    for (int mi = 0; mi < 4; ++mi) aR[mi] = RD_A(1, mi + 4);
    STAGE_B(nbuf, 1, koff);
    raw_barrier();
    MFMA_CLUSTER(4);
    wait_vmcnt4();   // ks0 of next tile landed (read at its p0)
    raw_barrier();
  }
  // epilogue
#pragma unroll
  for (int ni = 0; ni < 4; ++ni) {
    const int gcol = tn * 256 + wn * 64 + ni * 16 + lc;
    const float bias = b1[e * F_ + gcol];
#pragma unroll
    for (int mi = 0; mi < 8; ++mi)
#pragma unroll
      for (int r = 0; r < 4; ++r) {
        const int slot = base + wm * 128 + mi * 16 + lg * 4 + r;
        const float v = acc[mi][ni][r] + bias;
        const float g = 0.5f * v * (1.f + erff(v * 0.70710678118654752f));
        h[(size_t)slot * F_ + gcol] = f2bf(g);
      }
  }
}

// GEMM2: out[tok[slot],d] += gate[slot] * ( sum_f h[slot,f]*W2t[e][d,f] + b2[e][d] )
__global__ __launch_bounds__(512, 2) void gemm2_kernel(
    const u16* __restrict__ h, const u16* __restrict__ w2t,
    const float* __restrict__ b2, const int* __restrict__ tok,
    const float* __restrict__ gate, const int* __restrict__ off,
    float* __restrict__ out) {
  __shared__ __align__(16) u16 As[32768];
  __shared__ __align__(16) u16 Bs[32768];
  const int b = blockIdx.x;
  const int xcd = b & 7;
  const int local = b >> 3;            // 0..35
  const int tn = local & 3;            // 4 N-tiles (D/256)
  const int tm = xcd * 9 + (local >> 2);
  const int base = tm * 256;
  if (base >= off[E_]) return;
  int e = 0;
#pragma unroll
  for (int i = 1; i < E_; ++i) if (base >= off[i]) e = i;

  const int t = threadIdx.x;
  const int w = t >> 6, l = t & 63;
  const int srow = w * 32 + (l >> 2);
  const int scol = ((l & 3) ^ ((l >> 3) & 3)) * 8;
  const u16* gA0 = h + (size_t)(base + srow) * F_ + scol;
  const u16* gA1 = h + (size_t)(base + srow + 16) * F_ + scol;
  const int nr = tn * 256 + srow;
  const u16* gB0 = w2t + ((size_t)e * D_ + nr) * F_ + scol;
  const u16* gB1 = w2t + ((size_t)e * D_ + nr + 16) * F_ + scol;
  const int wm = w >> 2, wn = w & 3;
  const int lc = l & 15, lg = l >> 4;
  const int kch8 = (lg ^ ((lc >> 1) & 3)) * 8;

  f32x4 acc[8][4];
#pragma unroll
  for (int i = 0; i < 8; ++i)
#pragma unroll
    for (int j = 0; j < 4; ++j) acc[i][j] = (f32x4)(0.f);

  STAGE_A(0, 0, 0);
  STAGE_B(0, 0, 0);
  STAGE_A(0, 1, 0);
  STAGE_B(0, 1, 0);
  wait_vmcnt4();
  raw_barrier();

  const int KT = F_ / 64;  // 32
  for (int kt = 0; kt < KT; ++kt) {
    const int buf = kt & 1, nbuf = buf ^ 1;
    const int bufo = buf * 16384;
    const int koff = ((kt + 1 < KT) ? kt + 1 : kt) * 64;
    short8 aR[4], bR[4];
    // ---- p0 ----
#pragma unroll
    for (int mi = 0; mi < 4; ++mi) aR[mi] = RD_A(0, mi);
#pragma unroll
    for (int ni = 0; ni < 4; ++ni) bR[ni] = RD_B(0, ni);
    STAGE_A(nbuf, 0, koff);
    raw_barrier();
    MFMA_CLUSTER(0);
    raw_barrier();
    // ---- p1 ----
#pragma unroll
    for (int mi = 0; mi < 4; ++mi) aR[mi] = RD_A(0, mi + 4);
    STAGE_B(nbuf, 0, koff);
    raw_barrier();
    MFMA_CLUSTER(4);
    wait_vmcnt4();
    raw_barrier();
    // ---- p2 ----
#pragma unroll
    for (int mi = 0; mi < 4; ++mi) aR[mi] = RD_A(1, mi);
#pragma unroll
    for (int ni = 0; ni < 4; ++ni) bR[ni] = RD_B(1, ni);
    STAGE_A(nbuf, 1, koff);
    raw_barrier();
    MFMA_CLUSTER(0);
    raw_barrier();
    // ---- p3 ----
#pragma unroll
    for (int mi = 0; mi < 4; ++mi) aR[mi] = RD_A(1, mi + 4);
    STAGE_B(nbuf, 1, koff);
    raw_barrier();
    MFMA_CLUSTER(4);
    wait_vmcnt4();
    raw_barrier();
  }
#pragma unroll
  for (int ni = 0; ni < 4; ++ni) {
    const int gcol = tn * 256 + wn * 64 + ni * 16 + lc;
    const float bias = b2[e * D_ + gcol];
#pragma unroll
    for (int mi = 0; mi < 8; ++mi)
#pragma unroll
      for (int r = 0; r < 4; ++r) {
        const int slot = base + wm * 128 + mi * 16 + lg * 4 + r;
        const float gt = gate[slot];
        const int tk = tok[slot];
        const float v = gt * (acc[mi][ni][r] + bias);
        unsafeAtomicAdd(&out[(size_t)tk * D_ + gcol], v);
      }
  }
}

// ---------------- launch ----------------
extern "C" void kernel_launch(void* const* d_in, const int* in_sizes, int n_in,
                              void* d_out, int out_size, void* d_ws, size_t ws_size,
                              hipStream_t stream) {
  const float* x  = (const float*)d_in[0];
  const float* Wr = (const float*)d_in[1];
  const float* W1 = (const float*)d_in[2];
  const float* b1 = (const float*)d_in[3];
  const float* W2 = (const float*)d_in[4];
  const float* b2 = (const float*)d_in[5];
  float* out = (float*)d_out;

  char* p = (char*)d_ws;
  u16* xb  = (u16*)p;  p += (size_t)N_ * D_ * 2;
  u16* w1t = (u16*)p;  p += (size_t)E_ * D_ * F_ * 2;
  u16* w2t = (u16*)p;  p += (size_t)E_ * D_ * F_ * 2;
  u16* h   = (u16*)p;  p += (size_t)MAX_SLOTS * F_ * 2;
  int*   texp  = (int*)p;   p += (size_t)N_ * 2 * 4;
  float* tgate = (float*)p; p += (size_t)N_ * 2 * 4;
  int*   tok   = (int*)p;   p += (size_t)MAX_SLOTS * 4;
  float* gate  = (float*)p; p += (size_t)MAX_SLOTS * 4;
  int* counts  = (int*)p;
  int* off     = counts + E_;
  int* cursors = off + E_ + 1;

  hipMemsetAsync(counts, 0, (E_ + E_ + 1 + E_) * sizeof(int), stream);
  hipMemsetAsync(out, 0, (size_t)out_size * sizeof(float), stream);

  router_kernel<<<N_ / 4, 256, 0, stream>>>(x, Wr, texp, tgate, counts);
  offsets_kernel<<<1, 64, 0, stream>>>(counts, off, cursors);
  initslots_kernel<<<MAX_SLOTS / 256, 256, 0, stream>>>(tok, gate);
  place_kernel<<<N_ / 256, 256, 0, stream>>>(texp, tgate, cursors, tok, gate);

  cast_x_kernel<<<(N_ * D_ / 4) / 256, 256, 0, stream>>>(x, xb);
  transpose_cast_kernel<<<dim3(F_ / 64, D_ / 64, E_), 256, 0, stream>>>(W1, w1t, D_, F_);
  transpose_cast_kernel<<<dim3(D_ / 64, F_ / 64, E_), 256, 0, stream>>>(W2, w2t, F_, D_);

  gemm1_kernel<<<dim3(8 * MAX_MTILES), 512, 0, stream>>>(xb, w1t, b1, tok, off, h);
  gemm2_kernel<<<dim3(4 * MAX_MTILES), 512, 0, stream>>>(h, w2t, b2, tok, gate, off, out);
}

// Round 4
// 769.488 us; speedup vs baseline: 1.1639x; 1.1639x over previous
//
#include <hip/hip_runtime.h>
#include <hip/hip_bf16.h>
#include <math.h>

// MoE top-2, E=8, D=1024, F=2048, N=8192 tokens.
// R3: XOR-swizzled LDS staging layout (bank conflicts 8.65M -> 0).
// R4: depth-2 prefetch (3 LDS buffers). Neutral -> latency depth not binding.
// R5: 256^2 8-phase port. REGRESSED (1 blk/CU, 2-round grid, overlap not
//     reproduced). Reverted.
// R6: R4 base, ONE barrier per K-step instead of two. Ledger: with 3 buffers,
//     prefetch(kt+2 -> buf (kt+2)%3) issued AFTER barrier(kt) is safe because
//     every wave passed barrier(kt) only after MFMA(kt-1), which consumed all
//     its reads of buf (kt-1)%3 == (kt+2)%3. The remaining barrier (after
//     vmcnt(4)) is required so all waves' tile-kt loads have landed before
//     any wave reads the shared tile. Also: router now writes xb directly
//     (cast_x removed), offsets+initslots merged (one launch fewer).
// R7: identical resubmit of R6 -- previous round died to container-acquire
//     infra failure (no kernel evidence); ledger re-audited, no deadlock path.

#define E_ 8
#define D_ 1024
#define F_ 2048
#define N_ 8192
#define MAX_MTILES 136                 // ceil((N*K + E*127)/128)
#define MAX_SLOTS (MAX_MTILES * 128)   // 17408

typedef __attribute__((ext_vector_type(8))) short short8;
typedef __attribute__((ext_vector_type(4))) float f32x4;
typedef unsigned short u16;

__device__ __forceinline__ u16 f2bf(float f) {
  unsigned int u = __float_as_uint(f);
  unsigned int r = (u + 0x7fffu + ((u >> 16) & 1u)) >> 16;  // RNE
  return (u16)r;
}

__device__ __forceinline__ void gload_lds16(const void* g, void* lds) {
  __builtin_amdgcn_global_load_lds(
      (const __attribute__((address_space(1))) unsigned int*)g,
      (__attribute__((address_space(3))) unsigned int*)lds,
      16, 0, 0);
}

__device__ __forceinline__ void raw_barrier() {
  asm volatile("s_barrier" ::: "memory");
}
__device__ __forceinline__ void wait_vmcnt4() {
  asm volatile("s_waitcnt vmcnt(4)" ::: "memory");
}

// ---------------- router: one wave per token; also emits bf16 x ----------
__global__ __launch_bounds__(256) void router_kernel(
    const float* __restrict__ x, const float* __restrict__ Wr,
    int* __restrict__ texp, float* __restrict__ tgate, int* __restrict__ counts,
    u16* __restrict__ xb) {
  const int token = blockIdx.x * 4 + (threadIdx.x >> 6);
  const int lane = threadIdx.x & 63;
  const float4* xr = (const float4*)(x + (size_t)token * D_);
  ushort4* xbr = (ushort4*)(xb + (size_t)token * D_);
  float acc[E_];
#pragma unroll
  for (int e = 0; e < E_; ++e) acc[e] = 0.f;
#pragma unroll
  for (int it = 0; it < 4; ++it) {
    const int c4 = it * 64 + lane;
    const float4 xv = xr[c4];
    ushort4 o;
    o.x = f2bf(xv.x); o.y = f2bf(xv.y); o.z = f2bf(xv.z); o.w = f2bf(xv.w);
    xbr[c4] = o;
#pragma unroll
    for (int e = 0; e < E_; ++e) {
      const float4 wv = ((const float4*)(Wr + e * D_))[c4];
      acc[e] += xv.x * wv.x + xv.y * wv.y + xv.z * wv.z + xv.w * wv.w;
    }
  }
#pragma unroll
  for (int e = 0; e < E_; ++e)
#pragma unroll
    for (int s = 32; s > 0; s >>= 1) acc[e] += __shfl_xor(acc[e], s, 64);
  if (lane == 0) {
    int e0 = 0;
#pragma unroll
    for (int e = 1; e < E_; ++e) if (acc[e] > acc[e0]) e0 = e;
    int e1 = (e0 == 0) ? 1 : 0;
#pragma unroll
    for (int e = 0; e < E_; ++e) if (e != e0 && acc[e] > acc[e1]) e1 = e;
    const float g0 = 1.f / (1.f + __expf(acc[e1] - acc[e0]));
    texp[2 * token] = e0; texp[2 * token + 1] = e1;
    tgate[2 * token] = g0; tgate[2 * token + 1] = 1.f - g0;
    atomicAdd(&counts[e0], 1);
    atomicAdd(&counts[e1], 1);
  }
}

// offsets (1 thread) + slot init, one launch
__global__ void meta_kernel(const int* __restrict__ counts,
                            int* __restrict__ off, int* __restrict__ cursors,
                            int* __restrict__ tok, float* __restrict__ gate) {
  const int s = blockIdx.x * 256 + threadIdx.x;
  tok[s] = 0;
  gate[s] = 0.f;
  if (blockIdx.x == 0 && threadIdx.x == 0) {
    int o = 0;
    for (int e = 0; e < E_; ++e) {
      off[e] = o; cursors[e] = o;
      o += (counts[e] + 127) & ~127;
    }
    off[E_] = o;
  }
}

__global__ void place_kernel(const int* __restrict__ texp, const float* __restrict__ tgate,
                             int* __restrict__ cursors, int* __restrict__ tok,
                             float* __restrict__ gate) {
  const int n = blockIdx.x * 256 + threadIdx.x;
  if (n >= N_) return;
#pragma unroll
  for (int k = 0; k < 2; ++k) {
    const int e = texp[2 * n + k];
    const int p = atomicAdd(&cursors[e], 1);
    tok[p] = n;
    gate[p] = tgate[2 * n + k];
  }
}

// in[e][r][c] (fp32) -> out[e][c][r] (bf16); 64x64 tiles, coalesced both sides.
__global__ __launch_bounds__(256) void transpose_cast_kernel(
    const float* __restrict__ in, u16* __restrict__ out, int R, int C) {
  __shared__ float tile[64][65];
  const int e = blockIdx.z;
  const int c0 = blockIdx.x * 64, r0 = blockIdx.y * 64;
  const float* src = in + (size_t)e * R * C;
  u16* dst = out + (size_t)e * R * C;
  const int t = threadIdx.x;
  const int rr = t >> 4;        // 0..15
  const int cc = t & 15;        // 0..15
#pragma unroll
  for (int p = 0; p < 4; ++p) {
    const int r = rr + p * 16;
    const float4 v = *(const float4*)&src[(size_t)(r0 + r) * C + c0 + cc * 4];
    tile[r][cc * 4 + 0] = v.x; tile[r][cc * 4 + 1] = v.y;
    tile[r][cc * 4 + 2] = v.z; tile[r][cc * 4 + 3] = v.w;
  }
  __syncthreads();
#pragma unroll
  for (int p = 0; p < 4; ++p) {
    const int c = rr + p * 16;       // dst row = source col
    const int j = cc * 4;
    ushort4 o;
    o.x = f2bf(tile[j + 0][c]);
    o.y = f2bf(tile[j + 1][c]);
    o.z = f2bf(tile[j + 2][c]);
    o.w = f2bf(tile[j + 3][c]);
    *(ushort4*)&dst[(size_t)(c0 + c) * R + r0 + j] = o;
  }
}

// ---------------- grouped GEMMs: 128x128 tile, BK=32, 3-buf, 1 barrier/K ---
// GEMM1: h[slot,f] = gelu( sum_d xb[tok[slot],d] * W1t[e][f,d] + b1[e][f] )
__global__ __launch_bounds__(256) void gemm1_kernel(
    const u16* __restrict__ xb, const u16* __restrict__ w1t,
    const float* __restrict__ b1, const int* __restrict__ tok,
    const int* __restrict__ off, u16* __restrict__ h) {
  __shared__ __align__(16) u16 As[3 * 4096];
  __shared__ __align__(16) u16 Bs[3 * 4096];
  const int b = blockIdx.x;
  const int xcd = b & 7;
  const int local = b >> 3;            // 0..271
  const int tn = local & 15;           // 16 N-tiles (F/128)
  const int tm = xcd * 17 + (local >> 4);
  const int base = tm * 128;
  if (base >= off[E_]) return;
  int e = 0;
#pragma unroll
  for (int i = 1; i < E_; ++i) if (base >= off[i]) e = i;

  const int t = threadIdx.x;
  const int w = t >> 6, l = t & 63;
  const int arow = t >> 2;                         // 0..63
  const int acol = (((t & 3) ^ ((t >> 3) & 3)) * 8);  // swizzled colgroup
  const int tok0 = tok[base + arow];
  const int tok1 = tok[base + 64 + arow];
  const u16* gA0 = xb + (size_t)tok0 * D_ + acol;
  const u16* gA1 = xb + (size_t)tok1 * D_ + acol;
  const int f0 = tn * 128 + arow;
  const u16* gB0 = w1t + ((size_t)e * F_ + f0) * D_ + acol;
  const u16* gB1 = w1t + ((size_t)e * F_ + f0 + 64) * D_ + acol;

  const int wm = w >> 1, wn = w & 1;
  const int lc = l & 15, lg = l >> 4;
  const int swz = (lc >> 1) & 3;            // = ((row>>1)&3) for row = ..+lc
  const int kofs = ((lg ^ swz) * 8);        // swizzled K-chunk within row

  f32x4 acc[4][4];
#pragma unroll
  for (int i = 0; i < 4; ++i)
#pragma unroll
    for (int j = 0; j < 4; ++j) acc[i][j] = (f32x4)(0.f);

  // prologue: stage tiles 0 and 1 (depth-2)
  {
    gload_lds16(gA0, &As[w * 512]);
    gload_lds16(gA1, &As[2048 + w * 512]);
    gload_lds16(gB0, &Bs[w * 512]);
    gload_lds16(gB1, &Bs[2048 + w * 512]);
    gload_lds16(gA0 + 32, &As[4096 + w * 512]);
    gload_lds16(gA1 + 32, &As[4096 + 2048 + w * 512]);
    gload_lds16(gB0 + 32, &Bs[4096 + w * 512]);
    gload_lds16(gB1 + 32, &Bs[4096 + 2048 + w * 512]);
  }

  const int KT = D_ / 32;  // 32
  int cb = 0, pb = 2;      // compute buffer kt%3, prefetch buffer (kt+2)%3
  for (int kt = 0; kt < KT; ++kt) {
    wait_vmcnt4();   // my tile-kt loads landed (tile kt+1's 4 stay in flight)
    raw_barrier();   // => ALL waves' tile-kt loads landed; all reads of
                     //    buf (kt-1)%3 consumed (MFMA(kt-1) done)
    short8 a[4], bb[4];
#pragma unroll
    for (int mi = 0; mi < 4; ++mi)
      a[mi] = *(const short8*)&As[cb * 4096 + (wm * 64 + mi * 16 + lc) * 32 + kofs];
#pragma unroll
    for (int ni = 0; ni < 4; ++ni)
      bb[ni] = *(const short8*)&Bs[cb * 4096 + (wn * 64 + ni * 16 + lc) * 32 + kofs];
    // prefetch tile kt+2 into pb=(kt+2)%3 (==(kt-1)%3, consumed -- safe).
    // tail: clamped redundant reload keeps the vmcnt ledger uniform.
    {
      const int k0 = ((kt + 2 < KT) ? kt + 2 : KT - 1) * 32;
      gload_lds16(gA0 + k0, &As[pb * 4096 + w * 512]);
      gload_lds16(gA1 + k0, &As[pb * 4096 + 2048 + w * 512]);
      gload_lds16(gB0 + k0, &Bs[pb * 4096 + w * 512]);
      gload_lds16(gB1 + k0, &Bs[pb * 4096 + 2048 + w * 512]);
    }
#pragma unroll
    for (int mi = 0; mi < 4; ++mi)
#pragma unroll
      for (int ni = 0; ni < 4; ++ni)
        acc[mi][ni] = __builtin_amdgcn_mfma_f32_16x16x32_bf16(a[mi], bb[ni], acc[mi][ni], 0, 0, 0);
    cb = (cb + 1 == 3) ? 0 : cb + 1;
    pb = (pb + 1 == 3) ? 0 : pb + 1;
  }
#pragma unroll
  for (int ni = 0; ni < 4; ++ni) {
    const int gcol = tn * 128 + wn * 64 + ni * 16 + lc;
    const float bias = b1[e * F_ + gcol];
#pragma unroll
    for (int mi = 0; mi < 4; ++mi)
#pragma unroll
      for (int r = 0; r < 4; ++r) {
        const int slot = base + wm * 64 + mi * 16 + lg * 4 + r;
        const float v = acc[mi][ni][r] + bias;
        const float g = 0.5f * v * (1.f + erff(v * 0.70710678118654752f));
        h[(size_t)slot * F_ + gcol] = f2bf(g);
      }
  }
}

// GEMM2: out[tok[slot],d] += gate[slot] * ( sum_f h[slot,f]*W2t[e][d,f] + b2[e][d] )
__global__ __launch_bounds__(256) void gemm2_kernel(
    const u16* __restrict__ h, const u16* __restrict__ w2t,
    const float* __restrict__ b2, const int* __restrict__ tok,
    const float* __restrict__ gate, const int* __restrict__ off,
    float* __restrict__ out) {
  __shared__ __align__(16) u16 As[3 * 4096];
  __shared__ __align__(16) u16 Bs[3 * 4096];
  const int b = blockIdx.x;
  const int xcd = b & 7;
  const int local = b >> 3;            // 0..135
  const int tn = local & 7;            // 8 N-tiles (D/128)
  const int tm = xcd * 17 + (local >> 3);
  const int base = tm * 128;
  if (base >= off[E_]) return;
  int e = 0;
#pragma unroll
  for (int i = 1; i < E_; ++i) if (base >= off[i]) e = i;

  const int t = threadIdx.x;
  const int w = t >> 6, l = t & 63;
  const int arow = t >> 2;
  const int acol = (((t & 3) ^ ((t >> 3) & 3)) * 8);  // swizzled colgroup
  const u16* gA0 = h + (size_t)(base + arow) * F_ + acol;
  const u16* gA1 = h + (size_t)(base + 64 + arow) * F_ + acol;
  const int d0 = tn * 128 + arow;
  const u16* gB0 = w2t + ((size_t)e * D_ + d0) * F_ + acol;
  const u16* gB1 = w2t + ((size_t)e * D_ + d0 + 64) * F_ + acol;

  const int wm = w >> 1, wn = w & 1;
  const int lc = l & 15, lg = l >> 4;
  const int swz = (lc >> 1) & 3;
  const int kofs = ((lg ^ swz) * 8);

  f32x4 acc[4][4];
#pragma unroll
  for (int i = 0; i < 4; ++i)
#pragma unroll
    for (int j = 0; j < 4; ++j) acc[i][j] = (f32x4)(0.f);

  // prologue: stage tiles 0 and 1 (depth-2)
  {
    gload_lds16(gA0, &As[w * 512]);
    gload_lds16(gA1, &As[2048 + w * 512]);
    gload_lds16(gB0, &Bs[w * 512]);
    gload_lds16(gB1, &Bs[2048 + w * 512]);
    gload_lds16(gA0 + 32, &As[4096 + w * 512]);
    gload_lds16(gA1 + 32, &As[4096 + 2048 + w * 512]);
    gload_lds16(gB0 + 32, &Bs[4096 + w * 512]);
    gload_lds16(gB1 + 32, &Bs[4096 + 2048 + w * 512]);
  }

  const int KT = F_ / 32;  // 64
  int cb = 0, pb = 2;
  for (int kt = 0; kt < KT; ++kt) {
    wait_vmcnt4();
    raw_barrier();
    short8 a[4], bb[4];
#pragma unroll
    for (int mi = 0; mi < 4; ++mi)
      a[mi] = *(const short8*)&As[cb * 4096 + (wm * 64 + mi * 16 + lc) * 32 + kofs];
#pragma unroll
    for (int ni = 0; ni < 4; ++ni)
      bb[ni] = *(const short8*)&Bs[cb * 4096 + (wn * 64 + ni * 16 + lc) * 32 + kofs];
    {
      const int k0 = ((kt + 2 < KT) ? kt + 2 : KT - 1) * 32;
      gload_lds16(gA0 + k0, &As[pb * 4096 + w * 512]);
      gload_lds16(gA1 + k0, &As[pb * 4096 + 2048 + w * 512]);
      gload_lds16(gB0 + k0, &Bs[pb * 4096 + w * 512]);
      gload_lds16(gB1 + k0, &Bs[pb * 4096 + 2048 + w * 512]);
    }
#pragma unroll
    for (int mi = 0; mi < 4; ++mi)
#pragma unroll
      for (int ni = 0; ni < 4; ++ni)
        acc[mi][ni] = __builtin_amdgcn_mfma_f32_16x16x32_bf16(a[mi], bb[ni], acc[mi][ni], 0, 0, 0);
    cb = (cb + 1 == 3) ? 0 : cb + 1;
    pb = (pb + 1 == 3) ? 0 : pb + 1;
  }
#pragma unroll
  for (int ni = 0; ni < 4; ++ni) {
    const int gcol = tn * 128 + wn * 64 + ni * 16 + lc;
    const float bias = b2[e * D_ + gcol];
#pragma unroll
    for (int mi = 0; mi < 4; ++mi)
#pragma unroll
      for (int r = 0; r < 4; ++r) {
        const int slot = base + wm * 64 + mi * 16 + lg * 4 + r;
        const float gt = gate[slot];
        const int tk = tok[slot];
        const float v = gt * (acc[mi][ni][r] + bias);
        unsafeAtomicAdd(&out[(size_t)tk * D_ + gcol], v);
      }
  }
}

// ---------------- launch ----------------
extern "C" void kernel_launch(void* const* d_in, const int* in_sizes, int n_in,
                              void* d_out, int out_size, void* d_ws, size_t ws_size,
                              hipStream_t stream) {
  const float* x  = (const float*)d_in[0];
  const float* Wr = (const float*)d_in[1];
  const float* W1 = (const float*)d_in[2];
  const float* b1 = (const float*)d_in[3];
  const float* W2 = (const float*)d_in[4];
  const float* b2 = (const float*)d_in[5];
  float* out = (float*)d_out;

  char* p = (char*)d_ws;
  u16* xb  = (u16*)p;  p += (size_t)N_ * D_ * 2;
  u16* w1t = (u16*)p;  p += (size_t)E_ * D_ * F_ * 2;
  u16* w2t = (u16*)p;  p += (size_t)E_ * D_ * F_ * 2;
  u16* h   = (u16*)p;  p += (size_t)MAX_SLOTS * F_ * 2;
  int*   texp  = (int*)p;   p += (size_t)N_ * 2 * 4;
  float* tgate = (float*)p; p += (size_t)N_ * 2 * 4;
  int*   tok   = (int*)p;   p += (size_t)MAX_SLOTS * 4;
  float* gate  = (float*)p; p += (size_t)MAX_SLOTS * 4;
  int* counts  = (int*)p;
  int* off     = counts + E_;
  int* cursors = off + E_ + 1;

  hipMemsetAsync(counts, 0, (E_ + E_ + 1 + E_) * sizeof(int), stream);
  hipMemsetAsync(out, 0, (size_t)out_size * sizeof(float), stream);

  router_kernel<<<N_ / 4, 256, 0, stream>>>(x, Wr, texp, tgate, counts, xb);
  meta_kernel<<<MAX_SLOTS / 256, 256, 0, stream>>>(counts, off, cursors, tok, gate);
  place_kernel<<<N_ / 256, 256, 0, stream>>>(texp, tgate, cursors, tok, gate);

  transpose_cast_kernel<<<dim3(F_ / 64, D_ / 64, E_), 256, 0, stream>>>(W1, w1t, D_, F_);
  transpose_cast_kernel<<<dim3(D_ / 64, F_ / 64, E_), 256, 0, stream>>>(W2, w2t, F_, D_);

  gemm1_kernel<<<dim3(16 * MAX_MTILES), 256, 0, stream>>>(xb, w1t, b1, tok, off, h);
  gemm2_kernel<<<dim3(8 * MAX_MTILES), 256, 0, stream>>>(h, w2t, b2, tok, gate, off, out);
}

// Round 5
// 726.140 us; speedup vs baseline: 1.2333x; 1.0597x over previous
//
#include <hip/hip_runtime.h>
#include <hip/hip_bf16.h>
#include <math.h>

// MoE top-2, E=8, D=1024, F=2048, N=8192 tokens.
// R3: XOR-swizzled LDS staging (bank conflicts 8.65M -> 0).
// R4: depth-2 prefetch (3 LDS buffers). Neutral.
// R5: 256^2 8-phase port. REGRESSED. Reverted.
// R6/R7: single barrier per K-step (+5%); router emits xb; fewer launches.
// R8: occupancy attack. R7 profile: VGPR 88 arch + 64 acc = 152/wave ->
//     (128,256] bucket -> 2 waves/SIMD -> 2 blocks/CU (measured 17% occ).
//     Split the 128x128 tile across 8 waves (512-thr blocks): per-wave
//     acc 4x2 frags = 32 AGPR, ~90 total regs -> (64,128] bucket ->
//     4 waves/SIMD -> 16 waves/CU (2x residency). Same tile/pipeline/
//     swizzle/single-barrier ledger, staging now 2 gload_lds per wave.

#define E_ 8
#define D_ 1024
#define F_ 2048
#define N_ 8192
#define MAX_MTILES 136                 // ceil((N*K + E*127)/128)
#define MAX_SLOTS (MAX_MTILES * 128)   // 17408

typedef __attribute__((ext_vector_type(8))) short short8;
typedef __attribute__((ext_vector_type(4))) float f32x4;
typedef unsigned short u16;

__device__ __forceinline__ u16 f2bf(float f) {
  unsigned int u = __float_as_uint(f);
  unsigned int r = (u + 0x7fffu + ((u >> 16) & 1u)) >> 16;  // RNE
  return (u16)r;
}

__device__ __forceinline__ void gload_lds16(const void* g, void* lds) {
  __builtin_amdgcn_global_load_lds(
      (const __attribute__((address_space(1))) unsigned int*)g,
      (__attribute__((address_space(3))) unsigned int*)lds,
      16, 0, 0);
}

__device__ __forceinline__ void raw_barrier() {
  asm volatile("s_barrier" ::: "memory");
}
__device__ __forceinline__ void wait_vmcnt2() {
  asm volatile("s_waitcnt vmcnt(2)" ::: "memory");
}

// ---------------- router: one wave per token; also emits bf16 x ----------
__global__ __launch_bounds__(256) void router_kernel(
    const float* __restrict__ x, const float* __restrict__ Wr,
    int* __restrict__ texp, float* __restrict__ tgate, int* __restrict__ counts,
    u16* __restrict__ xb) {
  const int token = blockIdx.x * 4 + (threadIdx.x >> 6);
  const int lane = threadIdx.x & 63;
  const float4* xr = (const float4*)(x + (size_t)token * D_);
  ushort4* xbr = (ushort4*)(xb + (size_t)token * D_);
  float acc[E_];
#pragma unroll
  for (int e = 0; e < E_; ++e) acc[e] = 0.f;
#pragma unroll
  for (int it = 0; it < 4; ++it) {
    const int c4 = it * 64 + lane;
    const float4 xv = xr[c4];
    ushort4 o;
    o.x = f2bf(xv.x); o.y = f2bf(xv.y); o.z = f2bf(xv.z); o.w = f2bf(xv.w);
    xbr[c4] = o;
#pragma unroll
    for (int e = 0; e < E_; ++e) {
      const float4 wv = ((const float4*)(Wr + e * D_))[c4];
      acc[e] += xv.x * wv.x + xv.y * wv.y + xv.z * wv.z + xv.w * wv.w;
    }
  }
#pragma unroll
  for (int e = 0; e < E_; ++e)
#pragma unroll
    for (int s = 32; s > 0; s >>= 1) acc[e] += __shfl_xor(acc[e], s, 64);
  if (lane == 0) {
    int e0 = 0;
#pragma unroll
    for (int e = 1; e < E_; ++e) if (acc[e] > acc[e0]) e0 = e;
    int e1 = (e0 == 0) ? 1 : 0;
#pragma unroll
    for (int e = 0; e < E_; ++e) if (e != e0 && acc[e] > acc[e1]) e1 = e;
    const float g0 = 1.f / (1.f + __expf(acc[e1] - acc[e0]));
    texp[2 * token] = e0; texp[2 * token + 1] = e1;
    tgate[2 * token] = g0; tgate[2 * token + 1] = 1.f - g0;
    atomicAdd(&counts[e0], 1);
    atomicAdd(&counts[e1], 1);
  }
}

// offsets (1 thread) + slot init, one launch
__global__ void meta_kernel(const int* __restrict__ counts,
                            int* __restrict__ off, int* __restrict__ cursors,
                            int* __restrict__ tok, float* __restrict__ gate) {
  const int s = blockIdx.x * 256 + threadIdx.x;
  tok[s] = 0;
  gate[s] = 0.f;
  if (blockIdx.x == 0 && threadIdx.x == 0) {
    int o = 0;
    for (int e = 0; e < E_; ++e) {
      off[e] = o; cursors[e] = o;
      o += (counts[e] + 127) & ~127;
    }
    off[E_] = o;
  }
}

__global__ void place_kernel(const int* __restrict__ texp, const float* __restrict__ tgate,
                             int* __restrict__ cursors, int* __restrict__ tok,
                             float* __restrict__ gate) {
  const int n = blockIdx.x * 256 + threadIdx.x;
  if (n >= N_) return;
#pragma unroll
  for (int k = 0; k < 2; ++k) {
    const int e = texp[2 * n + k];
    const int p = atomicAdd(&cursors[e], 1);
    tok[p] = n;
    gate[p] = tgate[2 * n + k];
  }
}

// in[e][r][c] (fp32) -> out[e][c][r] (bf16); 64x64 tiles, coalesced both sides.
__global__ __launch_bounds__(256) void transpose_cast_kernel(
    const float* __restrict__ in, u16* __restrict__ out, int R, int C) {
  __shared__ float tile[64][65];
  const int e = blockIdx.z;
  const int c0 = blockIdx.x * 64, r0 = blockIdx.y * 64;
  const float* src = in + (size_t)e * R * C;
  u16* dst = out + (size_t)e * R * C;
  const int t = threadIdx.x;
  const int rr = t >> 4;        // 0..15
  const int cc = t & 15;        // 0..15
#pragma unroll
  for (int p = 0; p < 4; ++p) {
    const int r = rr + p * 16;
    const float4 v = *(const float4*)&src[(size_t)(r0 + r) * C + c0 + cc * 4];
    tile[r][cc * 4 + 0] = v.x; tile[r][cc * 4 + 1] = v.y;
    tile[r][cc * 4 + 2] = v.z; tile[r][cc * 4 + 3] = v.w;
  }
  __syncthreads();
#pragma unroll
  for (int p = 0; p < 4; ++p) {
    const int c = rr + p * 16;       // dst row = source col
    const int j = cc * 4;
    ushort4 o;
    o.x = f2bf(tile[j + 0][c]);
    o.y = f2bf(tile[j + 1][c]);
    o.z = f2bf(tile[j + 2][c]);
    o.w = f2bf(tile[j + 3][c]);
    *(ushort4*)&dst[(size_t)(c0 + c) * R + r0 + j] = o;
  }
}

// ------ grouped GEMMs: 128x128 tile, BK=32, 3-buf, 1 barrier/K, 8 waves ----
// Staging: wave w stages rows [w*16, w*16+16) of the A-tile and B-tile
// (one gload_lds each, 1KB). lane l: row w*16+(l>>2), phys chunk (l&3),
// source chunk (l&3)^((l>>3)&3) (same involution as R3; read side below).
// Read: row ..+lc, phys chunk lg^((lc>>1)&3).
// vmcnt ledger (per wave, 2 loads/tile): prologue 4 outstanding (tiles 0,1);
// iter kt: wait vmcnt(2) -> tile kt landed; barrier; ds_read; prefetch
// kt+2 (back to 4); MFMA. Single-barrier safety as R6 (prefetch into
// (kt+2)%3 == (kt-1)%3, consumed before barrier(kt)).

// GEMM1: h[slot,f] = gelu( sum_d xb[tok[slot],d] * W1t[e][f,d] + b1[e][f] )
__global__ __launch_bounds__(512, 4) void gemm1_kernel(
    const u16* __restrict__ xb, const u16* __restrict__ w1t,
    const float* __restrict__ b1, const int* __restrict__ tok,
    const int* __restrict__ off, u16* __restrict__ h) {
  __shared__ __align__(16) u16 As[3 * 4096];
  __shared__ __align__(16) u16 Bs[3 * 4096];
  const int b = blockIdx.x;
  const int xcd = b & 7;
  const int local = b >> 3;            // 0..271
  const int tn = local & 15;           // 16 N-tiles (F/128)
  const int tm = xcd * 17 + (local >> 4);
  const int base = tm * 128;
  if (base >= off[E_]) return;
  int e = 0;
#pragma unroll
  for (int i = 1; i < E_; ++i) if (base >= off[i]) e = i;

  const int t = threadIdx.x;
  const int w = t >> 6, l = t & 63;
  // staging source (per-wave 16 rows of A and of B)
  const int srow = w * 16 + (l >> 2);
  const int scol = ((l & 3) ^ ((l >> 3) & 3)) * 8;   // swizzled 16B chunk
  const u16* gA = xb + (size_t)tok[base + srow] * D_ + scol;
  const u16* gB = w1t + ((size_t)e * F_ + tn * 128 + srow) * D_ + scol;
  // compute-side ids: 2 M-waves x 4 N-waves; per-wave 64x32 output
  const int wm = w >> 2, wn = w & 3;
  const int lc = l & 15, lg = l >> 4;
  const int kofs = ((lg ^ ((lc >> 1) & 3)) * 8);

  f32x4 acc[4][2];
#pragma unroll
  for (int i = 0; i < 4; ++i)
#pragma unroll
    for (int j = 0; j < 2; ++j) acc[i][j] = (f32x4)(0.f);

  // prologue: stage tiles 0 and 1 (depth-2)
  gload_lds16(gA, &As[w * 512]);
  gload_lds16(gB, &Bs[w * 512]);
  gload_lds16(gA + 32, &As[4096 + w * 512]);
  gload_lds16(gB + 32, &Bs[4096 + w * 512]);

  const int KT = D_ / 32;  // 32
  int cb = 0, pb = 2;      // compute buffer kt%3, prefetch buffer (kt+2)%3
  for (int kt = 0; kt < KT; ++kt) {
    wait_vmcnt2();   // my tile-kt loads landed (tile kt+1's 2 in flight)
    raw_barrier();   // all waves' tile-kt loads landed; buf (kt-1)%3 consumed
    short8 a[4], bb[2];
#pragma unroll
    for (int mi = 0; mi < 4; ++mi)
      a[mi] = *(const short8*)&As[cb * 4096 + (wm * 64 + mi * 16 + lc) * 32 + kofs];
#pragma unroll
    for (int ni = 0; ni < 2; ++ni)
      bb[ni] = *(const short8*)&Bs[cb * 4096 + (wn * 32 + ni * 16 + lc) * 32 + kofs];
    // prefetch tile kt+2 into pb=(kt+2)%3 (==(kt-1)%3, consumed -- safe).
    {
      const int k0 = ((kt + 2 < KT) ? kt + 2 : KT - 1) * 32;
      gload_lds16(gA + k0, &As[pb * 4096 + w * 512]);
      gload_lds16(gB + k0, &Bs[pb * 4096 + w * 512]);
    }
#pragma unroll
    for (int mi = 0; mi < 4; ++mi)
#pragma unroll
      for (int ni = 0; ni < 2; ++ni)
        acc[mi][ni] = __builtin_amdgcn_mfma_f32_16x16x32_bf16(a[mi], bb[ni], acc[mi][ni], 0, 0, 0);
    cb = (cb + 1 == 3) ? 0 : cb + 1;
    pb = (pb + 1 == 3) ? 0 : pb + 1;
  }
#pragma unroll
  for (int ni = 0; ni < 2; ++ni) {
    const int gcol = tn * 128 + wn * 32 + ni * 16 + lc;
    const float bias = b1[e * F_ + gcol];
#pragma unroll
    for (int mi = 0; mi < 4; ++mi)
#pragma unroll
      for (int r = 0; r < 4; ++r) {
        const int slot = base + wm * 64 + mi * 16 + lg * 4 + r;
        const float v = acc[mi][ni][r] + bias;
        const float g = 0.5f * v * (1.f + erff(v * 0.70710678118654752f));
        h[(size_t)slot * F_ + gcol] = f2bf(g);
      }
  }
}

// GEMM2: out[tok[slot],d] += gate[slot] * ( sum_f h[slot,f]*W2t[e][d,f] + b2[e][d] )
__global__ __launch_bounds__(512, 4) void gemm2_kernel(
    const u16* __restrict__ h, const u16* __restrict__ w2t,
    const float* __restrict__ b2, const int* __restrict__ tok,
    const float* __restrict__ gate, const int* __restrict__ off,
    float* __restrict__ out) {
  __shared__ __align__(16) u16 As[3 * 4096];
  __shared__ __align__(16) u16 Bs[3 * 4096];
  const int b = blockIdx.x;
  const int xcd = b & 7;
  const int local = b >> 3;            // 0..135
  const int tn = local & 7;            // 8 N-tiles (D/128)
  const int tm = xcd * 17 + (local >> 3);
  const int base = tm * 128;
  if (base >= off[E_]) return;
  int e = 0;
#pragma unroll
  for (int i = 1; i < E_; ++i) if (base >= off[i]) e = i;

  const int t = threadIdx.x;
  const int w = t >> 6, l = t & 63;
  const int srow = w * 16 + (l >> 2);
  const int scol = ((l & 3) ^ ((l >> 3) & 3)) * 8;
  const u16* gA = h + (size_t)(base + srow) * F_ + scol;
  const u16* gB = w2t + ((size_t)e * D_ + tn * 128 + srow) * F_ + scol;
  const int wm = w >> 2, wn = w & 3;
  const int lc = l & 15, lg = l >> 4;
  const int kofs = ((lg ^ ((lc >> 1) & 3)) * 8);

  f32x4 acc[4][2];
#pragma unroll
  for (int i = 0; i < 4; ++i)
#pragma unroll
    for (int j = 0; j < 2; ++j) acc[i][j] = (f32x4)(0.f);

  gload_lds16(gA, &As[w * 512]);
  gload_lds16(gB, &Bs[w * 512]);
  gload_lds16(gA + 32, &As[4096 + w * 512]);
  gload_lds16(gB + 32, &Bs[4096 + w * 512]);

  const int KT = F_ / 32;  // 64
  int cb = 0, pb = 2;
  for (int kt = 0; kt < KT; ++kt) {
    wait_vmcnt2();
    raw_barrier();
    short8 a[4], bb[2];
#pragma unroll
    for (int mi = 0; mi < 4; ++mi)
      a[mi] = *(const short8*)&As[cb * 4096 + (wm * 64 + mi * 16 + lc) * 32 + kofs];
#pragma unroll
    for (int ni = 0; ni < 2; ++ni)
      bb[ni] = *(const short8*)&Bs[cb * 4096 + (wn * 32 + ni * 16 + lc) * 32 + kofs];
    {
      const int k0 = ((kt + 2 < KT) ? kt + 2 : KT - 1) * 32;
      gload_lds16(gA + k0, &As[pb * 4096 + w * 512]);
      gload_lds16(gB + k0, &Bs[pb * 4096 + w * 512]);
    }
#pragma unroll
    for (int mi = 0; mi < 4; ++mi)
#pragma unroll
      for (int ni = 0; ni < 2; ++ni)
        acc[mi][ni] = __builtin_amdgcn_mfma_f32_16x16x32_bf16(a[mi], bb[ni], acc[mi][ni], 0, 0, 0);
    cb = (cb + 1 == 3) ? 0 : cb + 1;
    pb = (pb + 1 == 3) ? 0 : pb + 1;
  }
#pragma unroll
  for (int ni = 0; ni < 2; ++ni) {
    const int gcol = tn * 128 + wn * 32 + ni * 16 + lc;
    const float bias = b2[e * D_ + gcol];
#pragma unroll
    for (int mi = 0; mi < 4; ++mi)
#pragma unroll
      for (int r = 0; r < 4; ++r) {
        const int slot = base + wm * 64 + mi * 16 + lg * 4 + r;
        const float gt = gate[slot];
        const int tk = tok[slot];
        const float v = gt * (acc[mi][ni][r] + bias);
        unsafeAtomicAdd(&out[(size_t)tk * D_ + gcol], v);
      }
  }
}

// ---------------- launch ----------------
extern "C" void kernel_launch(void* const* d_in, const int* in_sizes, int n_in,
                              void* d_out, int out_size, void* d_ws, size_t ws_size,
                              hipStream_t stream) {
  const float* x  = (const float*)d_in[0];
  const float* Wr = (const float*)d_in[1];
  const float* W1 = (const float*)d_in[2];
  const float* b1 = (const float*)d_in[3];
  const float* W2 = (const float*)d_in[4];
  const float* b2 = (const float*)d_in[5];
  float* out = (float*)d_out;

  char* p = (char*)d_ws;
  u16* xb  = (u16*)p;  p += (size_t)N_ * D_ * 2;
  u16* w1t = (u16*)p;  p += (size_t)E_ * D_ * F_ * 2;
  u16* w2t = (u16*)p;  p += (size_t)E_ * D_ * F_ * 2;
  u16* h   = (u16*)p;  p += (size_t)MAX_SLOTS * F_ * 2;
  int*   texp  = (int*)p;   p += (size_t)N_ * 2 * 4;
  float* tgate = (float*)p; p += (size_t)N_ * 2 * 4;
  int*   tok   = (int*)p;   p += (size_t)MAX_SLOTS * 4;
  float* gate  = (float*)p; p += (size_t)MAX_SLOTS * 4;
  int* counts  = (int*)p;
  int* off     = counts + E_;
  int* cursors = off + E_ + 1;

  hipMemsetAsync(counts, 0, (E_ + E_ + 1 + E_) * sizeof(int), stream);
  hipMemsetAsync(out, 0, (size_t)out_size * sizeof(float), stream);

  router_kernel<<<N_ / 4, 256, 0, stream>>>(x, Wr, texp, tgate, counts, xb);
  meta_kernel<<<MAX_SLOTS / 256, 256, 0, stream>>>(counts, off, cursors, tok, gate);
  place_kernel<<<N_ / 256, 256, 0, stream>>>(texp, tgate, cursors, tok, gate);

  transpose_cast_kernel<<<dim3(F_ / 64, D_ / 64, E_), 256, 0, stream>>>(W1, w1t, D_, F_);
  transpose_cast_kernel<<<dim3(D_ / 64, F_ / 64, E_), 256, 0, stream>>>(W2, w2t, F_, D_);

  gemm1_kernel<<<dim3(16 * MAX_MTILES), 512, 0, stream>>>(xb, w1t, b1, tok, off, h);
  gemm2_kernel<<<dim3(8 * MAX_MTILES), 512, 0, stream>>>(h, w2t, b2, tok, gate, off, out);
}

// Round 6
// 500.308 us; speedup vs baseline: 1.7901x; 1.4514x over previous
//
#include <hip/hip_runtime.h>
#include <hip/hip_bf16.h>
#include <math.h>

// MoE top-2, E=8, D=1024, F=2048, N=8192 tokens.
// R3: XOR-swizzled LDS staging (bank conflicts 8.65M -> 0).
// R4: depth-2 prefetch (3 LDS buffers). Neutral.
// R5: 256^2 8-phase port. REGRESSED. Reverted.
// R6/R7: single barrier per K-step (+5%); router emits xb; fewer launches.
// R8: 8-wave 512-thr gemm blocks (~90 regs/wave -> 4 waves/SIMD). 769->726.
// R9: aux-path atomics. R8 profile: router_kernel = 199us (HBM 2.2%,
//     VALU 3.4%) -- 16384 device atomics to ONE cache line (counts[0..7])
//     serialize at ~12ns each. Fix: per-block LDS histogram + per-line-
//     padded counters (counts[e*32]); place_kernel same disease, fixed via
//     block-level reservation (LDS two-pass, 256 global atomics total).

#define E_ 8
#define D_ 1024
#define F_ 2048
#define N_ 8192
#define MAX_MTILES 136                 // ceil((N*K + E*127)/128)
#define MAX_SLOTS (MAX_MTILES * 128)   // 17408
#define RT_TPB 16                      // router tokens per block

typedef __attribute__((ext_vector_type(8))) short short8;
typedef __attribute__((ext_vector_type(4))) float f32x4;
typedef unsigned short u16;

__device__ __forceinline__ u16 f2bf(float f) {
  unsigned int u = __float_as_uint(f);
  unsigned int r = (u + 0x7fffu + ((u >> 16) & 1u)) >> 16;  // RNE
  return (u16)r;
}

__device__ __forceinline__ void gload_lds16(const void* g, void* lds) {
  __builtin_amdgcn_global_load_lds(
      (const __attribute__((address_space(1))) unsigned int*)g,
      (__attribute__((address_space(3))) unsigned int*)lds,
      16, 0, 0);
}

__device__ __forceinline__ void raw_barrier() {
  asm volatile("s_barrier" ::: "memory");
}
__device__ __forceinline__ void wait_vmcnt2() {
  asm volatile("s_waitcnt vmcnt(2)" ::: "memory");
}

// ---------------- router: wave per token, 16 tokens/block ----------------
// Emits bf16 x; per-block LDS count histogram; 8 padded global atomics/block.
__global__ __launch_bounds__(256) void router_kernel(
    const float* __restrict__ x, const float* __restrict__ Wr,
    int* __restrict__ texp, float* __restrict__ tgate, int* __restrict__ counts,
    u16* __restrict__ xb) {
  __shared__ int lcnt[E_];
  if (threadIdx.x < E_) lcnt[threadIdx.x] = 0;
  __syncthreads();
  const int wid = threadIdx.x >> 6;
  const int lane = threadIdx.x & 63;
#pragma unroll
  for (int it = 0; it < RT_TPB / 4; ++it) {
    const int token = blockIdx.x * RT_TPB + it * 4 + wid;
    const float4* xr = (const float4*)(x + (size_t)token * D_);
    ushort4* xbr = (ushort4*)(xb + (size_t)token * D_);
    float acc[E_];
#pragma unroll
    for (int e = 0; e < E_; ++e) acc[e] = 0.f;
#pragma unroll
    for (int c = 0; c < 4; ++c) {
      const int c4 = c * 64 + lane;
      const float4 xv = xr[c4];
      ushort4 o;
      o.x = f2bf(xv.x); o.y = f2bf(xv.y); o.z = f2bf(xv.z); o.w = f2bf(xv.w);
      xbr[c4] = o;
#pragma unroll
      for (int e = 0; e < E_; ++e) {
        const float4 wv = ((const float4*)(Wr + e * D_))[c4];
        acc[e] += xv.x * wv.x + xv.y * wv.y + xv.z * wv.z + xv.w * wv.w;
      }
    }
#pragma unroll
    for (int e = 0; e < E_; ++e)
#pragma unroll
      for (int s = 32; s > 0; s >>= 1) acc[e] += __shfl_xor(acc[e], s, 64);
    if (lane == 0) {
      int e0 = 0;
#pragma unroll
      for (int e = 1; e < E_; ++e) if (acc[e] > acc[e0]) e0 = e;
      int e1 = (e0 == 0) ? 1 : 0;
#pragma unroll
      for (int e = 0; e < E_; ++e) if (e != e0 && acc[e] > acc[e1]) e1 = e;
      const float g0 = 1.f / (1.f + __expf(acc[e1] - acc[e0]));
      texp[2 * token] = e0; texp[2 * token + 1] = e1;
      tgate[2 * token] = g0; tgate[2 * token + 1] = 1.f - g0;
      atomicAdd(&lcnt[e0], 1);   // LDS, cheap
      atomicAdd(&lcnt[e1], 1);
    }
  }
  __syncthreads();
  if (threadIdx.x < E_)
    atomicAdd(&counts[threadIdx.x * 32], lcnt[threadIdx.x]);  // padded lines
}

// offsets (1 thread) + slot init, one launch
__global__ void meta_kernel(const int* __restrict__ counts,
                            int* __restrict__ off, int* __restrict__ cursors,
                            int* __restrict__ tok, float* __restrict__ gate) {
  const int s = blockIdx.x * 256 + threadIdx.x;
  tok[s] = 0;
  gate[s] = 0.f;
  if (blockIdx.x == 0 && threadIdx.x == 0) {
    int o = 0;
    for (int e = 0; e < E_; ++e) {
      off[e] = o; cursors[e * 32] = o;
      o += (counts[e * 32] + 127) & ~127;
    }
    off[E_] = o;
  }
}

// place: per-block two-pass LDS reservation; 8 padded global atomics/block.
__global__ __launch_bounds__(256) void place_kernel(
    const int* __restrict__ texp, const float* __restrict__ tgate,
    int* __restrict__ cursors, int* __restrict__ tok,
    float* __restrict__ gate) {
  __shared__ int cnt[E_], basee[E_], rk[E_];
  const int t = threadIdx.x;
  if (t < E_) { cnt[t] = 0; rk[t] = 0; }
  __syncthreads();
  const int n = blockIdx.x * 256 + t;
  const int e0 = texp[2 * n], e1 = texp[2 * n + 1];
  atomicAdd(&cnt[e0], 1);
  atomicAdd(&cnt[e1], 1);
  __syncthreads();
  if (t < E_) basee[t] = atomicAdd(&cursors[t * 32], cnt[t]);
  __syncthreads();
  {
    const int r = atomicAdd(&rk[e0], 1);
    const int p = basee[e0] + r;
    tok[p] = n; gate[p] = tgate[2 * n];
  }
  {
    const int r = atomicAdd(&rk[e1], 1);
    const int p = basee[e1] + r;
    tok[p] = n; gate[p] = tgate[2 * n + 1];
  }
}

// in[e][r][c] (fp32) -> out[e][c][r] (bf16); 64x64 tiles, coalesced both sides.
__global__ __launch_bounds__(256) void transpose_cast_kernel(
    const float* __restrict__ in, u16* __restrict__ out, int R, int C) {
  __shared__ float tile[64][65];
  const int e = blockIdx.z;
  const int c0 = blockIdx.x * 64, r0 = blockIdx.y * 64;
  const float* src = in + (size_t)e * R * C;
  u16* dst = out + (size_t)e * R * C;
  const int t = threadIdx.x;
  const int rr = t >> 4;        // 0..15
  const int cc = t & 15;        // 0..15
#pragma unroll
  for (int p = 0; p < 4; ++p) {
    const int r = rr + p * 16;
    const float4 v = *(const float4*)&src[(size_t)(r0 + r) * C + c0 + cc * 4];
    tile[r][cc * 4 + 0] = v.x; tile[r][cc * 4 + 1] = v.y;
    tile[r][cc * 4 + 2] = v.z; tile[r][cc * 4 + 3] = v.w;
  }
  __syncthreads();
#pragma unroll
  for (int p = 0; p < 4; ++p) {
    const int c = rr + p * 16;       // dst row = source col
    const int j = cc * 4;
    ushort4 o;
    o.x = f2bf(tile[j + 0][c]);
    o.y = f2bf(tile[j + 1][c]);
    o.z = f2bf(tile[j + 2][c]);
    o.w = f2bf(tile[j + 3][c]);
    *(ushort4*)&dst[(size_t)(c0 + c) * R + r0 + j] = o;
  }
}

// ------ grouped GEMMs: 128x128 tile, BK=32, 3-buf, 1 barrier/K, 8 waves ----
// (unchanged from R8 -- verified)

// GEMM1: h[slot,f] = gelu( sum_d xb[tok[slot],d] * W1t[e][f,d] + b1[e][f] )
__global__ __launch_bounds__(512, 4) void gemm1_kernel(
    const u16* __restrict__ xb, const u16* __restrict__ w1t,
    const float* __restrict__ b1, const int* __restrict__ tok,
    const int* __restrict__ off, u16* __restrict__ h) {
  __shared__ __align__(16) u16 As[3 * 4096];
  __shared__ __align__(16) u16 Bs[3 * 4096];
  const int b = blockIdx.x;
  const int xcd = b & 7;
  const int local = b >> 3;            // 0..271
  const int tn = local & 15;           // 16 N-tiles (F/128)
  const int tm = xcd * 17 + (local >> 4);
  const int base = tm * 128;
  if (base >= off[E_]) return;
  int e = 0;
#pragma unroll
  for (int i = 1; i < E_; ++i) if (base >= off[i]) e = i;

  const int t = threadIdx.x;
  const int w = t >> 6, l = t & 63;
  const int srow = w * 16 + (l >> 2);
  const int scol = ((l & 3) ^ ((l >> 3) & 3)) * 8;   // swizzled 16B chunk
  const u16* gA = xb + (size_t)tok[base + srow] * D_ + scol;
  const u16* gB = w1t + ((size_t)e * F_ + tn * 128 + srow) * D_ + scol;
  const int wm = w >> 2, wn = w & 3;
  const int lc = l & 15, lg = l >> 4;
  const int kofs = ((lg ^ ((lc >> 1) & 3)) * 8);

  f32x4 acc[4][2];
#pragma unroll
  for (int i = 0; i < 4; ++i)
#pragma unroll
    for (int j = 0; j < 2; ++j) acc[i][j] = (f32x4)(0.f);

  gload_lds16(gA, &As[w * 512]);
  gload_lds16(gB, &Bs[w * 512]);
  gload_lds16(gA + 32, &As[4096 + w * 512]);
  gload_lds16(gB + 32, &Bs[4096 + w * 512]);

  const int KT = D_ / 32;  // 32
  int cb = 0, pb = 2;
  for (int kt = 0; kt < KT; ++kt) {
    wait_vmcnt2();
    raw_barrier();
    short8 a[4], bb[2];
#pragma unroll
    for (int mi = 0; mi < 4; ++mi)
      a[mi] = *(const short8*)&As[cb * 4096 + (wm * 64 + mi * 16 + lc) * 32 + kofs];
#pragma unroll
    for (int ni = 0; ni < 2; ++ni)
      bb[ni] = *(const short8*)&Bs[cb * 4096 + (wn * 32 + ni * 16 + lc) * 32 + kofs];
    {
      const int k0 = ((kt + 2 < KT) ? kt + 2 : KT - 1) * 32;
      gload_lds16(gA + k0, &As[pb * 4096 + w * 512]);
      gload_lds16(gB + k0, &Bs[pb * 4096 + w * 512]);
    }
#pragma unroll
    for (int mi = 0; mi < 4; ++mi)
#pragma unroll
      for (int ni = 0; ni < 2; ++ni)
        acc[mi][ni] = __builtin_amdgcn_mfma_f32_16x16x32_bf16(a[mi], bb[ni], acc[mi][ni], 0, 0, 0);
    cb = (cb + 1 == 3) ? 0 : cb + 1;
    pb = (pb + 1 == 3) ? 0 : pb + 1;
  }
#pragma unroll
  for (int ni = 0; ni < 2; ++ni) {
    const int gcol = tn * 128 + wn * 32 + ni * 16 + lc;
    const float bias = b1[e * F_ + gcol];
#pragma unroll
    for (int mi = 0; mi < 4; ++mi)
#pragma unroll
      for (int r = 0; r < 4; ++r) {
        const int slot = base + wm * 64 + mi * 16 + lg * 4 + r;
        const float v = acc[mi][ni][r] + bias;
        const float g = 0.5f * v * (1.f + erff(v * 0.70710678118654752f));
        h[(size_t)slot * F_ + gcol] = f2bf(g);
      }
  }
}

// GEMM2: out[tok[slot],d] += gate[slot] * ( sum_f h[slot,f]*W2t[e][d,f] + b2[e][d] )
__global__ __launch_bounds__(512, 4) void gemm2_kernel(
    const u16* __restrict__ h, const u16* __restrict__ w2t,
    const float* __restrict__ b2, const int* __restrict__ tok,
    const float* __restrict__ gate, const int* __restrict__ off,
    float* __restrict__ out) {
  __shared__ __align__(16) u16 As[3 * 4096];
  __shared__ __align__(16) u16 Bs[3 * 4096];
  const int b = blockIdx.x;
  const int xcd = b & 7;
  const int local = b >> 3;            // 0..135
  const int tn = local & 7;            // 8 N-tiles (D/128)
  const int tm = xcd * 17 + (local >> 3);
  const int base = tm * 128;
  if (base >= off[E_]) return;
  int e = 0;
#pragma unroll
  for (int i = 1; i < E_; ++i) if (base >= off[i]) e = i;

  const int t = threadIdx.x;
  const int w = t >> 6, l = t & 63;
  const int srow = w * 16 + (l >> 2);
  const int scol = ((l & 3) ^ ((l >> 3) & 3)) * 8;
  const u16* gA = h + (size_t)(base + srow) * F_ + scol;
  const u16* gB = w2t + ((size_t)e * D_ + tn * 128 + srow) * F_ + scol;
  const int wm = w >> 2, wn = w & 3;
  const int lc = l & 15, lg = l >> 4;
  const int kofs = ((lg ^ ((lc >> 1) & 3)) * 8);

  f32x4 acc[4][2];
#pragma unroll
  for (int i = 0; i < 4; ++i)
#pragma unroll
    for (int j = 0; j < 2; ++j) acc[i][j] = (f32x4)(0.f);

  gload_lds16(gA, &As[w * 512]);
  gload_lds16(gB, &Bs[w * 512]);
  gload_lds16(gA + 32, &As[4096 + w * 512]);
  gload_lds16(gB + 32, &Bs[4096 + w * 512]);

  const int KT = F_ / 32;  // 64
  int cb = 0, pb = 2;
  for (int kt = 0; kt < KT; ++kt) {
    wait_vmcnt2();
    raw_barrier();
    short8 a[4], bb[2];
#pragma unroll
    for (int mi = 0; mi < 4; ++mi)
      a[mi] = *(const short8*)&As[cb * 4096 + (wm * 64 + mi * 16 + lc) * 32 + kofs];
#pragma unroll
    for (int ni = 0; ni < 2; ++ni)
      bb[ni] = *(const short8*)&Bs[cb * 4096 + (wn * 32 + ni * 16 + lc) * 32 + kofs];
    {
      const int k0 = ((kt + 2 < KT) ? kt + 2 : KT - 1) * 32;
      gload_lds16(gA + k0, &As[pb * 4096 + w * 512]);
      gload_lds16(gB + k0, &Bs[pb * 4096 + w * 512]);
    }
#pragma unroll
    for (int mi = 0; mi < 4; ++mi)
#pragma unroll
      for (int ni = 0; ni < 2; ++ni)
        acc[mi][ni] = __builtin_amdgcn_mfma_f32_16x16x32_bf16(a[mi], bb[ni], acc[mi][ni], 0, 0, 0);
    cb = (cb + 1 == 3) ? 0 : cb + 1;
    pb = (pb + 1 == 3) ? 0 : pb + 1;
  }
#pragma unroll
  for (int ni = 0; ni < 2; ++ni) {
    const int gcol = tn * 128 + wn * 32 + ni * 16 + lc;
    const float bias = b2[e * D_ + gcol];
#pragma unroll
    for (int mi = 0; mi < 4; ++mi)
#pragma unroll
      for (int r = 0; r < 4; ++r) {
        const int slot = base + wm * 64 + mi * 16 + lg * 4 + r;
        const float gt = gate[slot];
        const int tk = tok[slot];
        const float v = gt * (acc[mi][ni][r] + bias);
        unsafeAtomicAdd(&out[(size_t)tk * D_ + gcol], v);
      }
  }
}

// ---------------- launch ----------------
extern "C" void kernel_launch(void* const* d_in, const int* in_sizes, int n_in,
                              void* d_out, int out_size, void* d_ws, size_t ws_size,
                              hipStream_t stream) {
  const float* x  = (const float*)d_in[0];
  const float* Wr = (const float*)d_in[1];
  const float* W1 = (const float*)d_in[2];
  const float* b1 = (const float*)d_in[3];
  const float* W2 = (const float*)d_in[4];
  const float* b2 = (const float*)d_in[5];
  float* out = (float*)d_out;

  char* p = (char*)d_ws;
  u16* xb  = (u16*)p;  p += (size_t)N_ * D_ * 2;
  u16* w1t = (u16*)p;  p += (size_t)E_ * D_ * F_ * 2;
  u16* w2t = (u16*)p;  p += (size_t)E_ * D_ * F_ * 2;
  u16* h   = (u16*)p;  p += (size_t)MAX_SLOTS * F_ * 2;
  int*   texp  = (int*)p;   p += (size_t)N_ * 2 * 4;
  float* tgate = (float*)p; p += (size_t)N_ * 2 * 4;
  int*   tok   = (int*)p;   p += (size_t)MAX_SLOTS * 4;
  float* gate  = (float*)p; p += (size_t)MAX_SLOTS * 4;
  int* counts  = (int*)p;          // E_*32 ints (one 128B line per expert)
  int* off     = counts + E_ * 32; // E_+1 ints
  int* cursors = off + 16;         // E_*32 ints (padded lines)

  hipMemsetAsync(counts, 0, (E_ * 32 + 16 + E_ * 32) * sizeof(int), stream);
  hipMemsetAsync(out, 0, (size_t)out_size * sizeof(float), stream);

  router_kernel<<<N_ / RT_TPB, 256, 0, stream>>>(x, Wr, texp, tgate, counts, xb);
  meta_kernel<<<MAX_SLOTS / 256, 256, 0, stream>>>(counts, off, cursors, tok, gate);
  place_kernel<<<N_ / 256, 256, 0, stream>>>(texp, tgate, cursors, tok, gate);

  transpose_cast_kernel<<<dim3(F_ / 64, D_ / 64, E_), 256, 0, stream>>>(W1, w1t, D_, F_);
  transpose_cast_kernel<<<dim3(D_ / 64, F_ / 64, E_), 256, 0, stream>>>(W2, w2t, F_, D_);

  gemm1_kernel<<<dim3(16 * MAX_MTILES), 512, 0, stream>>>(xb, w1t, b1, tok, off, h);
  gemm2_kernel<<<dim3(8 * MAX_MTILES), 512, 0, stream>>>(h, w2t, b2, tok, gate, off, out);
}